// Round 17
// baseline (756.961 us; speedup 1.0000x reference)
//
#include <hip/hip_runtime.h>
#include <hip/hip_bf16.h>

#define SEQ 2048
#define DM 512
#define NHEAD 8
#define HDIM 64
#define DFFN 2048
#define PMTN 20

typedef __bf16 bf16x8 __attribute__((ext_vector_type(8)));
typedef float f32x4 __attribute__((ext_vector_type(4)));
typedef unsigned short u16x8 __attribute__((ext_vector_type(8)));

__device__ __forceinline__ float wave_sum(float v) {
#pragma unroll
  for (int off = 32; off; off >>= 1) v += __shfl_xor(v, off);
  return v;
}

__device__ __forceinline__ unsigned short f2b(float x) {
  __hip_bfloat16 h = __float2bfloat16(x);
  return *(unsigned short*)&h;
}

__device__ __forceinline__ void gll16(const __hip_bfloat16* g, __hip_bfloat16* l) {
  __builtin_amdgcn_global_load_lds(
      (const __attribute__((address_space(1))) unsigned int*)(g),
      (__attribute__((address_space(3))) unsigned int*)(l), 16, 0, 0);
}

// ---------------- fused prologue: embed | cast srb | rope table | mask bias --
__global__ __launch_bounds__(256) void prologue_kernel(
    const float* __restrict__ trg, const float* __restrict__ emb_w,
    const float* __restrict__ emb_b, float* __restrict__ X,
    const float* __restrict__ srb, __hip_bfloat16* __restrict__ SRBb,
    float2* __restrict__ rt, const float* __restrict__ mask,
    float* __restrict__ mb, int* __restrict__ mtflag) {
  const int b = blockIdx.x, t = threadIdx.x;
  if (b < 4096) {
    int idx = b * 256 + t;
    int r = idx >> 9, c = idx & 511;
    float t0 = trg[r * 3 + 0], t1 = trg[r * 3 + 1], t2 = trg[r * 3 + 2];
    X[idx] = t0 * emb_w[c] + t1 * emb_w[512 + c] + t2 * emb_w[1024 + c] + emb_b[c];
  } else if (b < 8192) {
    int i = (b - 4096) * 256 + t;
    SRBb[i] = __float2bfloat16(srb[i]);
  } else if (b < 8448) {
    int idx = (b - 8192) * 256 + t;
    int row = idx >> 5, i = idx & 31;
    float inv = __expf(-(float)i * (9.210340371976184f / 32.f));
    float sn, cs;
    sincosf((float)row * inv, &sn, &cs);
    rt[idx] = make_float2(cs, sn);
  } else {
    int i = (b - 8448) * 256 + t;
    bool masked = !(mask[i] > 0.f);
    mb[i] = masked ? -1.0e9f : 0.f;  // scaled-score (log2) domain
    unsigned long long any = __ballot(masked);
    if ((t & 63) == 0) mtflag[i >> 6] = (any != 0ull) ? 1 : 0;
  }
}

// ---------------- LN (bf16 out) | per-layer weight transpose, one dispatch --
__global__ __launch_bounds__(256) void ln_tr_kernel(
    const float* __restrict__ x, const float* __restrict__ g,
    const float* __restrict__ b, __hip_bfloat16* __restrict__ o,
    const float* __restrict__ wqkv, const float* __restrict__ wo,
    const float* __restrict__ cwqkv, const float* __restrict__ cwo,
    const float* __restrict__ w1, const float* __restrict__ w2,
    __hip_bfloat16* __restrict__ Wt) {
  const int t = threadIdx.x;
  if (blockIdx.x < 512) {
    int row = blockIdx.x * 4 + (t >> 6);
    int lane = t & 63;
    const float* xr = x + (long)row * DM;
    float v[8];
    float s = 0.f;
#pragma unroll
    for (int j = 0; j < 8; j++) { v[j] = xr[lane + 64 * j]; s += v[j]; }
    s = wave_sum(s);
    float mean = s * (1.f / DM);
    float q = 0.f;
#pragma unroll
    for (int j = 0; j < 8; j++) { float d = v[j] - mean; q += d * d; }
    q = wave_sum(q);
    float r = rsqrtf(q * (1.f / DM) + 1e-5f);
    __hip_bfloat16* orow = o + (long)row * DM;
#pragma unroll
    for (int j = 0; j < 8; j++) {
      int c = lane + 64 * j;
      orow[c] = __float2bfloat16((v[j] - mean) * r * g[c] + b[c]);
    }
    return;
  }
  __shared__ float T[64][65];
  int bb = blockIdx.x - 512;
  const float* W;
  __hip_bfloat16* O;
  int Kd, Nd;
  if (bb < 192)      { W = wqkv;  O = Wt + 0;       Kd = 512;  Nd = 1536; }
  else if (bb < 256) { W = wo;    O = Wt + 786432;  Kd = 512;  Nd = 512;  bb -= 192; }
  else if (bb < 448) { W = cwqkv; O = Wt + 1048576; Kd = 512;  Nd = 1536; bb -= 256; }
  else if (bb < 512) { W = cwo;   O = Wt + 1835008; Kd = 512;  Nd = 512;  bb -= 448; }
  else if (bb < 768) { W = w1;    O = Wt + 2097152; Kd = 512;  Nd = 2048; bb -= 512; }
  else               { W = w2;    O = Wt + 3145728; Kd = 2048; Nd = 512;  bb -= 768; }
  int tn = Nd >> 6;
  int k0 = (bb / tn) * 64, n0 = (bb % tn) * 64;
  int rr = t >> 4, c4 = (t & 15) * 4;
#pragma unroll
  for (int p = 0; p < 4; p++) {
    int row = rr + p * 16;
    float4 v = *(const float4*)(W + (long)(k0 + row) * Nd + n0 + c4);
    T[row][c4 + 0] = v.x; T[row][c4 + 1] = v.y;
    T[row][c4 + 2] = v.z; T[row][c4 + 3] = v.w;
  }
  __syncthreads();
#pragma unroll
  for (int p = 0; p < 4; p++) {
    int row = rr + p * 16;
    ushort4 pk;
    pk.x = f2b(T[c4 + 0][row]); pk.y = f2b(T[c4 + 1][row]);
    pk.z = f2b(T[c4 + 2][row]); pk.w = f2b(T[c4 + 3][row]);
    *(ushort4*)(O + (long)(n0 + row) * Kd + k0 + c4) = pk;
  }
}

// ---------------- plain LN (bf16 out): 4 rows / 256-thr block ---------------
__global__ __launch_bounds__(256) void ln_bf16_kernel(
    const float* __restrict__ x, const float* __restrict__ g,
    const float* __restrict__ b, __hip_bfloat16* __restrict__ o) {
  int row = blockIdx.x * 4 + (threadIdx.x >> 6);
  int lane = threadIdx.x & 63;
  const float* xr = x + (long)row * DM;
  float v[8];
  float s = 0.f;
#pragma unroll
  for (int j = 0; j < 8; j++) { v[j] = xr[lane + 64 * j]; s += v[j]; }
  s = wave_sum(s);
  float mean = s * (1.f / DM);
  float q = 0.f;
#pragma unroll
  for (int j = 0; j < 8; j++) { float d = v[j] - mean; q += d * d; }
  q = wave_sum(q);
  float r = rsqrtf(q * (1.f / DM) + 1e-5f);
  __hip_bfloat16* orow = o + (long)row * DM;
#pragma unroll
  for (int j = 0; j < 8; j++) {
    int c = lane + 64 * j;
    orow[c] = __float2bfloat16((v[j] - mean) * r * g[c] + b[c]);
  }
}

// ---------------- final LN + generator fused --------------------------------
__global__ __launch_bounds__(256) void ln_gen_kernel(
    const float* __restrict__ x, const float* __restrict__ g,
    const float* __restrict__ b, const float* __restrict__ gw,
    const float* __restrict__ gb, float* __restrict__ out) {
  int row = blockIdx.x * 4 + (threadIdx.x >> 6);
  int lane = threadIdx.x & 63;
  const float* xr = x + (long)row * DM;
  float v[8];
  float s = 0.f;
#pragma unroll
  for (int j = 0; j < 8; j++) { v[j] = xr[lane + 64 * j]; s += v[j]; }
  s = wave_sum(s);
  float mean = s * (1.f / DM);
  float q = 0.f;
#pragma unroll
  for (int j = 0; j < 8; j++) { float d = v[j] - mean; q += d * d; }
  q = wave_sum(q);
  float r = rsqrtf(q * (1.f / DM) + 1e-5f);
  float a0 = 0.f, a1 = 0.f, a2 = 0.f;
#pragma unroll
  for (int j = 0; j < 8; j++) {
    int c = lane + 64 * j;
    float nv = (v[j] - mean) * r * g[c] + b[c];
    a0 = fmaf(nv, gw[c * 3 + 0], a0);
    a1 = fmaf(nv, gw[c * 3 + 1], a1);
    a2 = fmaf(nv, gw[c * 3 + 2], a2);
  }
  a0 = wave_sum(a0);
  a1 = wave_sum(a1);
  a2 = wave_sum(a2);
  if (lane == 0) {
    out[row * 3 + 0] = a0 + gb[0];
    out[row * 3 + 1] = a1 + gb[1];
    out[row * 3 + 2] = a2 + gb[2];
  }
}

// ---------------- bf16 MFMA GEMM, 64x64 tile, BK=64, double-buffered (R8) ---
__global__ __launch_bounds__(256) void gemm_bf16_64(
    const __hip_bfloat16* __restrict__ A, int lda,
    const __hip_bfloat16* __restrict__ A2,
    const __hip_bfloat16* __restrict__ Bt, int ldb,
    const float* __restrict__ bias,
    const float* __restrict__ residual,
    float* __restrict__ Cf, __hip_bfloat16* __restrict__ Cb, int ldc,
    int K, int relu, int mode, const float2* __restrict__ rt,
    __hip_bfloat16* __restrict__ Qp, __hip_bfloat16* __restrict__ Kp,
    __hip_bfloat16* __restrict__ Vtp) {
  __shared__ __attribute__((aligned(16))) __hip_bfloat16 As[2][4096];
  __shared__ __attribute__((aligned(16))) __hip_bfloat16 Bs[2][4096];
  const int t = threadIdx.x;
  const int bx = blockIdx.x;
  const int nrow = bx * 64, m0 = blockIdx.y * 64;
  const int ptype = (mode == 0) ? 3 : (nrow < 512 ? 0 : (nrow < 1024 ? 1 : 2));
  const int head = (nrow >> 6) & 7;
  const __hip_bfloat16* Ause = (mode == 2 && bx >= 8) ? A2 : A;

  const int w = t >> 6, lane = t & 63;
  const int wr = w >> 1, wc = w & 1;
  const int fr = lane & 15, fk = lane >> 4;
  const int r0 = t & 63, c0 = t >> 6;
  const __hip_bfloat16* Arow = Ause + (long)(m0 + r0) * lda;
  const __hip_bfloat16* Brow = Bt + (long)(nrow + r0) * ldb;

  uint4 ra0 = *(const uint4*)(Arow + c0 * 8);
  uint4 ra1 = *(const uint4*)(Arow + (c0 + 4) * 8);
  uint4 rb0 = *(const uint4*)(Brow + c0 * 8);
  uint4 rb1 = *(const uint4*)(Brow + (c0 + 4) * 8);
  *(uint4*)(&As[0][(c0 * 64 + r0) * 8]) = ra0;
  *(uint4*)(&As[0][((c0 + 4) * 64 + r0) * 8]) = ra1;
  *(uint4*)(&Bs[0][(c0 * 64 + r0) * 8]) = rb0;
  *(uint4*)(&Bs[0][((c0 + 4) * 64 + r0) * 8]) = rb1;
  __syncthreads();

  f32x4 acc[2][2] = {};
  const int NK = K >> 6;
  for (int ks = 0; ks < NK; ++ks) {
    const int cur = ks & 1;
    if (ks + 1 < NK) {
      const int ko = (ks + 1) << 6;
      ra0 = *(const uint4*)(Arow + ko + c0 * 8);
      ra1 = *(const uint4*)(Arow + ko + (c0 + 4) * 8);
      rb0 = *(const uint4*)(Brow + ko + c0 * 8);
      rb1 = *(const uint4*)(Brow + ko + (c0 + 4) * 8);
    }
#pragma unroll
    for (int kk = 0; kk < 2; ++kk) {
      const int kc = kk * 4 + fk;
      bf16x8 a0 = *(const bf16x8*)(&As[cur][(kc * 64 + wr * 32 + fr) * 8]);
      bf16x8 a1 = *(const bf16x8*)(&As[cur][(kc * 64 + wr * 32 + 16 + fr) * 8]);
      bf16x8 b0 = *(const bf16x8*)(&Bs[cur][(kc * 64 + wc * 32 + fr) * 8]);
      bf16x8 b1 = *(const bf16x8*)(&Bs[cur][(kc * 64 + wc * 32 + 16 + fr) * 8]);
      acc[0][0] = __builtin_amdgcn_mfma_f32_16x16x32_bf16(a0, b0, acc[0][0], 0, 0, 0);
      acc[0][1] = __builtin_amdgcn_mfma_f32_16x16x32_bf16(a0, b1, acc[0][1], 0, 0, 0);
      acc[1][0] = __builtin_amdgcn_mfma_f32_16x16x32_bf16(a1, b0, acc[1][0], 0, 0, 0);
      acc[1][1] = __builtin_amdgcn_mfma_f32_16x16x32_bf16(a1, b1, acc[1][1], 0, 0, 0);
    }
    if (ks + 1 < NK) {
      const int nxt = cur ^ 1;
      *(uint4*)(&As[nxt][(c0 * 64 + r0) * 8]) = ra0;
      *(uint4*)(&As[nxt][((c0 + 4) * 64 + r0) * 8]) = ra1;
      *(uint4*)(&Bs[nxt][(c0 * 64 + r0) * 8]) = rb0;
      *(uint4*)(&Bs[nxt][((c0 + 4) * 64 + r0) * 8]) = rb1;
    }
    __syncthreads();
  }

  if (ptype == 3) {
#pragma unroll
    for (int m = 0; m < 2; ++m)
#pragma unroll
      for (int n = 0; n < 2; ++n)
#pragma unroll
        for (int j = 0; j < 4; ++j) {
          int r = m0 + wr * 32 + m * 16 + fk * 4 + j;
          int c = nrow + wc * 32 + n * 16 + fr;
          float v = acc[m][n][j] + bias[c];
          if (relu) v = fmaxf(v, 0.f);
          if (residual) v += residual[(long)r * ldc + c];
          if (Cf) Cf[(long)r * ldc + c] = v;
          if (Cb) Cb[(long)r * ldc + c] = __float2bfloat16(v);
        }
    return;
  }

  // ---- pack epilogue: stage tile (f32, XOR-swizzled) in LDS over As ----
  float* Lt = (float*)As;
#pragma unroll
  for (int m = 0; m < 2; ++m)
#pragma unroll
    for (int n = 0; n < 2; ++n)
#pragma unroll
      for (int j = 0; j < 4; ++j) {
        int rl = wr * 32 + m * 16 + fk * 4 + j;
        int cl = wc * 32 + n * 16 + fr;
        Lt[rl * 64 + (cl ^ (rl & 31))] = acc[m][n][j] + bias[nrow + cl];
      }
  __syncthreads();

  if (ptype == 2) {
    const int d = t >> 2, sc = (t & 3) * 16;
    u16x8 o0, o1;
#pragma unroll
    for (int s = 0; s < 8; s++) {
      o0[s] = f2b(Lt[(sc + s) * 64 + (d ^ ((sc + s) & 31))]);
      o1[s] = f2b(Lt[(sc + 8 + s) * 64 + (d ^ ((sc + 8 + s) & 31))]);
    }
    __hip_bfloat16* dst = Vtp + ((long)(head * 64 + d)) * SEQ + m0 + sc;
    *(u16x8*)dst = o0;
    *(u16x8*)(dst + 8) = o1;
  } else {
    const float QS = (ptype == 0) ? 0.18033688011112042f : 1.0f;
    const int r = t >> 2, i0 = (t & 3) * 8;
    const float2* rp = rt + (long)(m0 + r) * 32 + i0;
    u16x8 lo, hi;
#pragma unroll
    for (int p = 0; p < 8; p++) {
      float a = Lt[r * 64 + ((i0 + p) ^ (r & 31))];
      float b = Lt[r * 64 + ((i0 + p + 32) ^ (r & 31))];
      float2 cs = rp[p];
      lo[p] = f2b((a * cs.x - b * cs.y) * QS);
      hi[p] = f2b((a * cs.y + b * cs.x) * QS);
    }
    __hip_bfloat16* dst =
        (ptype == 0 ? Qp : Kp) + ((long)head * SEQ + m0 + r) * 64 + i0;
    *(u16x8*)dst = lo;
    *(u16x8*)(dst + 32) = hi;
  }
}

// ---------------- split-KV flash attention ----------------------------------
__global__ __launch_bounds__(256) void attn_part_kernel(
    const __hip_bfloat16* __restrict__ Qp, const __hip_bfloat16* __restrict__ Kp,
    const __hip_bfloat16* __restrict__ Vtp, const float* __restrict__ mbias,
    const int* __restrict__ mtflag,
    __hip_bfloat16* __restrict__ Op, float* __restrict__ Ml,
    int causal, int csz) {
  const int qt = blockIdx.x, ch = blockIdx.y, head = blockIdx.z;
  const int kv0 = ch * csz;
  if (causal && kv0 > qt * 64 + 63) return;
  const int kvlen = causal ? min(csz, qt * 64 + 64 - kv0) : csz;
  const int nt = (kvlen + 63) >> 6;

  __shared__ __attribute__((aligned(16))) __hip_bfloat16 Ks[2][4096];
  __shared__ __attribute__((aligned(16))) __hip_bfloat16 Vs[4096];
  __shared__ __attribute__((aligned(16))) __hip_bfloat16 Ps[4096];
  const int t = threadIdx.x, w = t >> 6, lane = t & 63;
  const int fr = lane & 15, fk = lane >> 4;
  const int qr = qt * 64 + w * 16 + fr;
  const int wq0 = qt * 64 + w * 16;

  bf16x8 qa0, qa1;
  {
    const __hip_bfloat16* qp = Qp + ((long)head * SEQ + qr) * 64 + fk * 8;
    qa0 = *(const bf16x8*)qp;
    qa1 = *(const bf16x8*)(qp + 32);
  }
  const __hip_bfloat16* Kh = Kp + (long)head * SEQ * 64;
  const __hip_bfloat16* Vh = Vtp + (long)head * 64 * SEQ;
  const int skr = t & 63, skc = t >> 6;

  float m_i = -3e38f, l_i = 0.f;
  f32x4 o_[4] = {};
  const int sw2 = (fr & 7) << 4;

  uint4 vr0, vr1;
  {
    const __hip_bfloat16* ksrc = Kh + (long)(kv0 + skr) * 64 + skc * 8;
    gll16(ksrc, Ks[0] + t * 8);
    gll16(ksrc + 32, Ks[0] + t * 8 + 2048);
    const __hip_bfloat16* vsrc = Vh + (long)skr * SEQ + kv0 + skc * 8;
    vr0 = *(const uint4*)vsrc;
    vr1 = *(const uint4*)(vsrc + 32);
  }

  for (int tile = 0; tile < nt; ++tile) {
    const int cur = tile & 1;
    __syncthreads();
    *(uint4*)(Vs + t * 8) = vr0;
    *(uint4*)(Vs + t * 8 + 2048) = vr1;
    __syncthreads();
    if (tile + 1 < nt) {
      const int kb1 = kv0 + (tile + 1) * 64;
      const int nxt = cur ^ 1;
      const __hip_bfloat16* ksrc = Kh + (long)(kb1 + skr) * 64 + skc * 8;
      gll16(ksrc, Ks[nxt] + t * 8);
      gll16(ksrc + 32, Ks[nxt] + t * 8 + 2048);
      const __hip_bfloat16* vsrc = Vh + (long)skr * SEQ + kb1 + skc * 8;
      vr0 = *(const uint4*)vsrc;
      vr1 = *(const uint4*)(vsrc + 32);
    }
    const int kb = kv0 + tile * 64;
    const bool need = !causal || (kb <= wq0 + 15);
    if (need) {
      const bool diag = causal && (kb + 63 > wq0);
      const bool hasmask = mtflag[kb >> 6] != 0;

      f32x4 sacc[4];
      __builtin_amdgcn_s_setprio(1);
#pragma unroll
      for (int n = 0; n < 4; n++) {
        bf16x8 ka0 = *(const bf16x8*)(Ks[cur] + fk * 512 + (n * 16 + fr) * 8);
        bf16x8 ka1 = *(const bf16x8*)(Ks[cur] + (4 + fk) * 512 + (n * 16 + fr) * 8);
        f32x4 zz = {};
        zz = __builtin_amdgcn_mfma_f32_16x16x32_bf16(ka0, qa0, zz, 0, 0, 0);
        sacc[n] = __builtin_amdgcn_mfma_f32_16x16x32_bf16(ka1, qa1, zz, 0, 0, 0);
      }
      __builtin_amdgcn_s_setprio(0);

      float sv[4][4];
      float rm = -3e38f;
#pragma unroll
      for (int n = 0; n < 4; n++) {
        const int ka = kb + n * 16 + fk * 4;
        if (hasmask) {
          float4 mb = *(const float4*)(mbias + ka);
          sv[n][0] = sacc[n][0] + mb.x;
          sv[n][1] = sacc[n][1] + mb.y;
          sv[n][2] = sacc[n][2] + mb.z;
          sv[n][3] = sacc[n][3] + mb.w;
        } else {
          sv[n][0] = sacc[n][0]; sv[n][1] = sacc[n][1];
          sv[n][2] = sacc[n][2]; sv[n][3] = sacc[n][3];
        }
        if (diag) {
#pragma unroll
          for (int j = 0; j < 4; j++)
            if (ka + j > qr) sv[n][j] = -3e38f;
        }
#pragma unroll
        for (int j = 0; j < 4; j++) rm = fmaxf(rm, sv[n][j]);
      }
      rm = fmaxf(rm, __shfl_xor(rm, 16));
      rm = fmaxf(rm, __shfl_xor(rm, 32));
      if (!__all(rm <= m_i)) {
        float nm = fmaxf(m_i, rm);
        float f = exp2f(m_i - nm);
        l_i *= f;
#pragma unroll
        for (int n = 0; n < 4; n++) o_[n] *= f;
        m_i = nm;
      }
#pragma unroll
      for (int n = 0; n < 4; n++) {
        float p0 = exp2f(sv[n][0] - m_i);
        float p1 = exp2f(sv[n][1] - m_i);
        float p2 = exp2f(sv[n][2] - m_i);
        float p3 = exp2f(sv[n][3] - m_i);
        l_i += (p0 + p1) + (p2 + p3);
        ushort4 pk4;
        pk4.x = f2b(p0); pk4.y = f2b(p1); pk4.z = f2b(p2); pk4.w = f2b(p3);
        *(ushort4*)((char*)Ps + ((w * 2048 + fr * 128 + (n * 16 + fk * 4) * 2) ^ sw2)) = pk4;
      }

      __builtin_amdgcn_s_setprio(1);
#pragma unroll
      for (int s = 0; s < 2; s++) {
        bf16x8 pb = *(const bf16x8*)((char*)Ps + ((w * 2048 + fr * 128 + s * 64 + fk * 16) ^ sw2));
#pragma unroll
        for (int n = 0; n < 4; n++) {
          bf16x8 va = *(const bf16x8*)(Vs + (s * 4 + fk) * 512 + (n * 16 + fr) * 8);
          o_[n] = __builtin_amdgcn_mfma_f32_16x16x32_bf16(va, pb, o_[n], 0, 0, 0);
        }
      }
      __builtin_amdgcn_s_setprio(0);
    }
  }

  l_i += __shfl_xor(l_i, 16);
  l_i += __shfl_xor(l_i, 32);

  const long bid = ((long)head * 32 + qt) * gridDim.y + ch;
  __hip_bfloat16* Ob = Op + bid * 4096;
#pragma unroll
  for (int n = 0; n < 4; n++) {
    ushort4 ov;
    ov.x = f2b(o_[n][0]); ov.y = f2b(o_[n][1]);
    ov.z = f2b(o_[n][2]); ov.w = f2b(o_[n][3]);
    *(ushort4*)(Ob + (w * 16 + fr) * 64 + n * 16 + fk * 4) = ov;
  }
  if (fk == 0) {
    float2 ml = make_float2(m_i, l_i);
    *(float2*)(Ml + bid * 128 + (w * 16 + fr) * 2) = ml;
  }
}

// ---------------- combine partials -> bf16 O --------------------------------
__global__ __launch_bounds__(256) void attn_combine_kernel(
    const __hip_bfloat16* __restrict__ Op, const float* __restrict__ Ml,
    __hip_bfloat16* __restrict__ O, int ldo, int causal, int csz, int nch) {
  const int qt = blockIdx.x, head = blockIdx.y;
  const int nc = causal ? min(nch, (qt * 64 + 63) / csz + 1) : nch;
  const int t = threadIdx.x;
  const int row = t >> 2, c16 = (t & 3) * 16;
  const long bid0 = ((long)head * 32 + qt) * nch;
  float M = -3e38f;
  for (int c = 0; c < nc; c++) M = fmaxf(M, Ml[(bid0 + c) * 128 + row * 2]);
  float L = 0.f;
  float acc[16] = {};
  for (int c = 0; c < nc; c++) {
    float2 ml = *(const float2*)(Ml + (bid0 + c) * 128 + row * 2);
    float wg = exp2f(ml.x - M);
    L += wg * ml.y;
    const __hip_bfloat16* base = Op + (bid0 + c) * 4096 + row * 64 + c16;
    bf16x8 a = *(const bf16x8*)base;
    bf16x8 b = *(const bf16x8*)(base + 8);
#pragma unroll
    for (int e = 0; e < 8; e++) {
      acc[e] += wg * (float)a[e];
      acc[8 + e] += wg * (float)b[e];
    }
  }
  float invL = 1.f / fmaxf(L, 1e-20f);
  u16x8 o0, o1;
#pragma unroll
  for (int e = 0; e < 8; e++) {
    o0[e] = f2b(acc[e] * invL);
    o1[e] = f2b(acc[8 + e] * invL);
  }
  __hip_bfloat16* orow = O + (long)(qt * 64 + row) * ldo + head * 64 + c16;
  *(u16x8*)orow = o0;
  *(u16x8*)(orow + 8) = o1;
}

extern "C" void kernel_launch(void* const* d_in, const int* in_sizes, int n_in,
                              void* d_out, int out_size, void* d_ws, size_t ws_size,
                              hipStream_t stream) {
  const float* trg      = (const float*)d_in[0];
  const float* src_rep  = (const float*)d_in[1];
  const float* src_mask = (const float*)d_in[2];
  const float* emb_w    = (const float*)d_in[3];
  const float* emb_b    = (const float*)d_in[4];
  const float* sa_wqkv  = (const float*)d_in[5];
  const float* sa_bqkv  = (const float*)d_in[6];
  const float* sa_wo    = (const float*)d_in[7];
  const float* sa_bo    = (const float*)d_in[8];
  const float* ca_wqkv  = (const float*)d_in[9];
  const float* ca_bqkv  = (const float*)d_in[10];
  const float* ca_wo    = (const float*)d_in[11];
  const float* ca_bo    = (const float*)d_in[12];
  const float* ffn_w1   = (const float*)d_in[13];
  const float* ffn_b1   = (const float*)d_in[14];
  const float* ffn_w2   = (const float*)d_in[15];
  const float* ffn_b2   = (const float*)d_in[16];
  const float* ln_g     = (const float*)d_in[17];
  const float* ln_b     = (const float*)d_in[18];
  const float* lnf_g    = (const float*)d_in[19];
  const float* lnf_b    = (const float*)d_in[20];
  const float* gen_w    = (const float*)d_in[21];
  const float* gen_b    = (const float*)d_in[22];

  const float* srb = src_rep + (long)PMTN * DM;

  char* wsb = (char*)d_ws;
  float*          X    = (float*)wsb;                              // [0,4M)
  __hip_bfloat16* Hb   = (__hip_bfloat16*)(wsb + (4ul << 20));     // [4,6)
  __hip_bfloat16* MID  = (__hip_bfloat16*)(wsb + (6ul << 20));     // [6,14)
  __hip_bfloat16* AO   = (__hip_bfloat16*)(wsb + (14ul << 20));    // [14,16)
  __hip_bfloat16* SRBb = (__hip_bfloat16*)(wsb + (16ul << 20));    // [16,18)
  float2*         rt   = (float2*)(wsb + (18ul << 20));            // 512K
  float*          mbias= (float*)(wsb + (18ul << 20) + 524288);    // 8K
  int*            mtfl = (int*)(wsb + (18ul << 20) + 532480);      // 128B
  float*          Ml   = (float*)(wsb + (19ul << 20));             // 1M (8 ch)
  __hip_bfloat16* Qp   = (__hip_bfloat16*)(wsb + (20ul << 20));    // 2M
  __hip_bfloat16* Kp   = (__hip_bfloat16*)(wsb + (22ul << 20));    // 2M
  __hip_bfloat16* Vtp  = (__hip_bfloat16*)(wsb + (24ul << 20));    // 2M
  __hip_bfloat16* Wt   = (__hip_bfloat16*)(wsb + (26ul << 20));    // 8M
  __hip_bfloat16* Op   = (__hip_bfloat16*)(wsb + (34ul << 20));    // 17M (8 ch)
  // requires ws >= 51MB; harness ws is ~268MB.

  const int nchS = 8, cszS = SEQ / nchS;  // self-attn: balanced 4-tile chunks
  const int nchC = 4, cszC = SEQ / nchC;  // cross-attn: uniform 8-tile chunks

  prologue_kernel<<<8456, 256, 0, stream>>>(trg, emb_w, emb_b, X, srb, SRBb,
                                            rt, src_mask, mbias, mtfl);

  __hip_bfloat16* wqkvT  = Wt + 0;
  __hip_bfloat16* woT    = Wt + 786432;
  __hip_bfloat16* cwqkvT = Wt + 1048576;
  __hip_bfloat16* cwoT   = Wt + 1835008;
  __hip_bfloat16* w1T    = Wt + 2097152;
  __hip_bfloat16* w2T    = Wt + 3145728;

  for (int li = 0; li < 4; li++) {
    const float* bqkv  = sa_bqkv + (long)li * 3 * DM;
    const float* bo    = sa_bo + (long)li * DM;
    const float* cbqkv = ca_bqkv + (long)li * 3 * DM;
    const float* cbo   = ca_bo + (long)li * DM;
    const float* b1    = ffn_b1 + (long)li * DFFN;
    const float* b2    = ffn_b2 + (long)li * DM;
    const float* g0  = ln_g + (long)(li * 3 + 0) * DM;
    const float* bb0 = ln_b + (long)(li * 3 + 0) * DM;
    const float* g1  = ln_g + (long)(li * 3 + 1) * DM;
    const float* bb1 = ln_b + (long)(li * 3 + 1) * DM;
    const float* g2  = ln_g + (long)(li * 3 + 2) * DM;
    const float* bb2 = ln_b + (long)(li * 3 + 2) * DM;

    // ---- self attention (LN + this layer's weight transposes fused) ----
    ln_tr_kernel<<<1536, 256, 0, stream>>>(
        X, g0, bb0, Hb,
        sa_wqkv + (long)li * DM * 3 * DM, sa_wo + (long)li * DM * DM,
        ca_wqkv + (long)li * DM * 3 * DM, ca_wo + (long)li * DM * DM,
        ffn_w1 + (long)li * DM * DFFN, ffn_w2 + (long)li * DFFN * DM, Wt);
    gemm_bf16_64<<<dim3(24, 32), 256, 0, stream>>>(
        Hb, DM, nullptr, wqkvT, DM, bqkv, nullptr, nullptr, nullptr, DM,
        DM, 0, 1, rt, Qp, Kp, Vtp);
    attn_part_kernel<<<dim3(32, nchS, 8), 256, 0, stream>>>(
        Qp, Kp, Vtp, mbias, mtfl, Op, Ml, 1, cszS);
    attn_combine_kernel<<<dim3(32, 8), 256, 0, stream>>>(
        Op, Ml, AO, DM, 1, cszS, nchS);
    gemm_bf16_64<<<dim3(8, 32), 256, 0, stream>>>(
        AO, DM, nullptr, woT, DM, bo, X, X, nullptr, DM,
        DM, 0, 0, nullptr, nullptr, nullptr, nullptr);

    // ---- cross attention (Q + KV in one dispatch) ----
    ln_bf16_kernel<<<512, 256, 0, stream>>>(X, g1, bb1, Hb);
    gemm_bf16_64<<<dim3(24, 32), 256, 0, stream>>>(
        Hb, DM, SRBb, cwqkvT, DM, cbqkv, nullptr, nullptr, nullptr, DM,
        DM, 0, 2, rt, Qp, Kp, Vtp);
    attn_part_kernel<<<dim3(32, nchC, 8), 256, 0, stream>>>(
        Qp, Kp, Vtp, mbias, mtfl, Op, Ml, 0, cszC);
    attn_combine_kernel<<<dim3(32, 8), 256, 0, stream>>>(
        Op, Ml, AO, DM, 0, cszC, nchC);
    gemm_bf16_64<<<dim3(8, 32), 256, 0, stream>>>(
        AO, DM, nullptr, cwoT, DM, cbo, X, X, nullptr, DM,
        DM, 0, 0, nullptr, nullptr, nullptr, nullptr);

    // ---- FFN ----
    ln_bf16_kernel<<<512, 256, 0, stream>>>(X, g2, bb2, Hb);
    gemm_bf16_64<<<dim3(32, 32), 256, 0, stream>>>(
        Hb, DM, nullptr, w1T, DM, b1, nullptr, nullptr, MID, DFFN,
        DM, 1, 0, nullptr, nullptr, nullptr, nullptr);
    gemm_bf16_64<<<dim3(8, 32), 256, 0, stream>>>(
        MID, DFFN, nullptr, w2T, DFFN, b2, X, X, nullptr, DM,
        DFFN, 0, 0, nullptr, nullptr, nullptr, nullptr);
  }

  ln_gen_kernel<<<512, 256, 0, stream>>>(X, lnf_g, lnf_b, gen_w, gen_b,
                                         (float*)d_out);
}

// Round 18
// 741.193 us; speedup vs baseline: 1.0213x; 1.0213x over previous
//
#include <hip/hip_runtime.h>
#include <hip/hip_bf16.h>

#define SEQ 2048
#define DM 512
#define NHEAD 8
#define HDIM 64
#define DFFN 2048
#define PMTN 20

typedef __bf16 bf16x8 __attribute__((ext_vector_type(8)));
typedef float f32x4 __attribute__((ext_vector_type(4)));
typedef unsigned short u16x8 __attribute__((ext_vector_type(8)));

__device__ __forceinline__ float wave_sum(float v) {
#pragma unroll
  for (int off = 32; off; off >>= 1) v += __shfl_xor(v, off);
  return v;
}

__device__ __forceinline__ unsigned short f2b(float x) {
  __hip_bfloat16 h = __float2bfloat16(x);
  return *(unsigned short*)&h;
}

__device__ __forceinline__ void gll16(const __hip_bfloat16* g, __hip_bfloat16* l) {
  __builtin_amdgcn_global_load_lds(
      (const __attribute__((address_space(1))) unsigned int*)(g),
      (__attribute__((address_space(3))) unsigned int*)(l), 16, 0, 0);
}

// ---------------- fused prologue: embed | cast srb | rope table | mask bias --
__global__ __launch_bounds__(256) void prologue_kernel(
    const float* __restrict__ trg, const float* __restrict__ emb_w,
    const float* __restrict__ emb_b, float* __restrict__ X,
    const float* __restrict__ srb, __hip_bfloat16* __restrict__ SRBb,
    float2* __restrict__ rt, const float* __restrict__ mask,
    float* __restrict__ mb, int* __restrict__ mtflag) {
  const int b = blockIdx.x, t = threadIdx.x;
  if (b < 4096) {
    int idx = b * 256 + t;
    int r = idx >> 9, c = idx & 511;
    float t0 = trg[r * 3 + 0], t1 = trg[r * 3 + 1], t2 = trg[r * 3 + 2];
    X[idx] = t0 * emb_w[c] + t1 * emb_w[512 + c] + t2 * emb_w[1024 + c] + emb_b[c];
  } else if (b < 8192) {
    int i = (b - 4096) * 256 + t;
    SRBb[i] = __float2bfloat16(srb[i]);
  } else if (b < 8448) {
    int idx = (b - 8192) * 256 + t;
    int row = idx >> 5, i = idx & 31;
    float inv = __expf(-(float)i * (9.210340371976184f / 32.f));
    float sn, cs;
    sincosf((float)row * inv, &sn, &cs);
    rt[idx] = make_float2(cs, sn);
  } else {
    int i = (b - 8448) * 256 + t;
    bool masked = !(mask[i] > 0.f);
    mb[i] = masked ? -1.0e9f : 0.f;  // scaled-score (log2) domain
    unsigned long long any = __ballot(masked);
    if ((t & 63) == 0) mtflag[i >> 6] = (any != 0ull) ? 1 : 0;
  }
}

// ---------------- LN (bf16 out) | per-layer weight transpose, one dispatch --
__global__ __launch_bounds__(256) void ln_tr_kernel(
    const float* __restrict__ x, const float* __restrict__ g,
    const float* __restrict__ b, __hip_bfloat16* __restrict__ o,
    const float* __restrict__ wqkv, const float* __restrict__ wo,
    const float* __restrict__ cwqkv, const float* __restrict__ cwo,
    const float* __restrict__ w1, const float* __restrict__ w2,
    __hip_bfloat16* __restrict__ Wt) {
  const int t = threadIdx.x;
  if (blockIdx.x < 512) {
    int row = blockIdx.x * 4 + (t >> 6);
    int lane = t & 63;
    const float* xr = x + (long)row * DM;
    float v[8];
    float s = 0.f;
#pragma unroll
    for (int j = 0; j < 8; j++) { v[j] = xr[lane + 64 * j]; s += v[j]; }
    s = wave_sum(s);
    float mean = s * (1.f / DM);
    float q = 0.f;
#pragma unroll
    for (int j = 0; j < 8; j++) { float d = v[j] - mean; q += d * d; }
    q = wave_sum(q);
    float r = rsqrtf(q * (1.f / DM) + 1e-5f);
    __hip_bfloat16* orow = o + (long)row * DM;
#pragma unroll
    for (int j = 0; j < 8; j++) {
      int c = lane + 64 * j;
      orow[c] = __float2bfloat16((v[j] - mean) * r * g[c] + b[c]);
    }
    return;
  }
  __shared__ float T[64][65];
  int bb = blockIdx.x - 512;
  const float* W;
  __hip_bfloat16* O;
  int Kd, Nd;
  if (bb < 192)      { W = wqkv;  O = Wt + 0;       Kd = 512;  Nd = 1536; }
  else if (bb < 256) { W = wo;    O = Wt + 786432;  Kd = 512;  Nd = 512;  bb -= 192; }
  else if (bb < 448) { W = cwqkv; O = Wt + 1048576; Kd = 512;  Nd = 1536; bb -= 256; }
  else if (bb < 512) { W = cwo;   O = Wt + 1835008; Kd = 512;  Nd = 512;  bb -= 448; }
  else if (bb < 768) { W = w1;    O = Wt + 2097152; Kd = 512;  Nd = 2048; bb -= 512; }
  else               { W = w2;    O = Wt + 3145728; Kd = 2048; Nd = 512;  bb -= 768; }
  int tn = Nd >> 6;
  int k0 = (bb / tn) * 64, n0 = (bb % tn) * 64;
  int rr = t >> 4, c4 = (t & 15) * 4;
#pragma unroll
  for (int p = 0; p < 4; p++) {
    int row = rr + p * 16;
    float4 v = *(const float4*)(W + (long)(k0 + row) * Nd + n0 + c4);
    T[row][c4 + 0] = v.x; T[row][c4 + 1] = v.y;
    T[row][c4 + 2] = v.z; T[row][c4 + 3] = v.w;
  }
  __syncthreads();
#pragma unroll
  for (int p = 0; p < 4; p++) {
    int row = rr + p * 16;
    ushort4 pk;
    pk.x = f2b(T[c4 + 0][row]); pk.y = f2b(T[c4 + 1][row]);
    pk.z = f2b(T[c4 + 2][row]); pk.w = f2b(T[c4 + 3][row]);
    *(ushort4*)(O + (long)(n0 + row) * Kd + k0 + c4) = pk;
  }
}

// ---------------- plain LN (bf16 out): 4 rows / 256-thr block ---------------
__global__ __launch_bounds__(256) void ln_bf16_kernel(
    const float* __restrict__ x, const float* __restrict__ g,
    const float* __restrict__ b, __hip_bfloat16* __restrict__ o) {
  int row = blockIdx.x * 4 + (threadIdx.x >> 6);
  int lane = threadIdx.x & 63;
  const float* xr = x + (long)row * DM;
  float v[8];
  float s = 0.f;
#pragma unroll
  for (int j = 0; j < 8; j++) { v[j] = xr[lane + 64 * j]; s += v[j]; }
  s = wave_sum(s);
  float mean = s * (1.f / DM);
  float q = 0.f;
#pragma unroll
  for (int j = 0; j < 8; j++) { float d = v[j] - mean; q += d * d; }
  q = wave_sum(q);
  float r = rsqrtf(q * (1.f / DM) + 1e-5f);
  __hip_bfloat16* orow = o + (long)row * DM;
#pragma unroll
  for (int j = 0; j < 8; j++) {
    int c = lane + 64 * j;
    orow[c] = __float2bfloat16((v[j] - mean) * r * g[c] + b[c]);
  }
}

// ---------------- final LN + generator fused --------------------------------
__global__ __launch_bounds__(256) void ln_gen_kernel(
    const float* __restrict__ x, const float* __restrict__ g,
    const float* __restrict__ b, const float* __restrict__ gw,
    const float* __restrict__ gb, float* __restrict__ out) {
  int row = blockIdx.x * 4 + (threadIdx.x >> 6);
  int lane = threadIdx.x & 63;
  const float* xr = x + (long)row * DM;
  float v[8];
  float s = 0.f;
#pragma unroll
  for (int j = 0; j < 8; j++) { v[j] = xr[lane + 64 * j]; s += v[j]; }
  s = wave_sum(s);
  float mean = s * (1.f / DM);
  float q = 0.f;
#pragma unroll
  for (int j = 0; j < 8; j++) { float d = v[j] - mean; q += d * d; }
  q = wave_sum(q);
  float r = rsqrtf(q * (1.f / DM) + 1e-5f);
  float a0 = 0.f, a1 = 0.f, a2 = 0.f;
#pragma unroll
  for (int j = 0; j < 8; j++) {
    int c = lane + 64 * j;
    float nv = (v[j] - mean) * r * g[c] + b[c];
    a0 = fmaf(nv, gw[c * 3 + 0], a0);
    a1 = fmaf(nv, gw[c * 3 + 1], a1);
    a2 = fmaf(nv, gw[c * 3 + 2], a2);
  }
  a0 = wave_sum(a0);
  a1 = wave_sum(a1);
  a2 = wave_sum(a2);
  if (lane == 0) {
    out[row * 3 + 0] = a0 + gb[0];
    out[row * 3 + 1] = a1 + gb[1];
    out[row * 3 + 2] = a2 + gb[2];
  }
}

// ---------------- bf16 MFMA GEMM, 64x64 tile, BK=64, double-buffered (R8) ---
__global__ __launch_bounds__(256) void gemm_bf16_64(
    const __hip_bfloat16* __restrict__ A, int lda,
    const __hip_bfloat16* __restrict__ A2,
    const __hip_bfloat16* __restrict__ Bt, int ldb,
    const float* __restrict__ bias,
    const float* __restrict__ residual,
    float* __restrict__ Cf, __hip_bfloat16* __restrict__ Cb, int ldc,
    int K, int relu, int mode, const float2* __restrict__ rt,
    __hip_bfloat16* __restrict__ Qp, __hip_bfloat16* __restrict__ Kp,
    __hip_bfloat16* __restrict__ Vtp) {
  __shared__ __attribute__((aligned(16))) __hip_bfloat16 As[2][4096];
  __shared__ __attribute__((aligned(16))) __hip_bfloat16 Bs[2][4096];
  const int t = threadIdx.x;
  const int bx = blockIdx.x;
  const int nrow = bx * 64, m0 = blockIdx.y * 64;
  const int ptype = (mode == 0) ? 3 : (nrow < 512 ? 0 : (nrow < 1024 ? 1 : 2));
  const int head = (nrow >> 6) & 7;
  const __hip_bfloat16* Ause = (mode == 2 && bx >= 8) ? A2 : A;

  const int w = t >> 6, lane = t & 63;
  const int wr = w >> 1, wc = w & 1;
  const int fr = lane & 15, fk = lane >> 4;
  const int r0 = t & 63, c0 = t >> 6;
  const __hip_bfloat16* Arow = Ause + (long)(m0 + r0) * lda;
  const __hip_bfloat16* Brow = Bt + (long)(nrow + r0) * ldb;

  uint4 ra0 = *(const uint4*)(Arow + c0 * 8);
  uint4 ra1 = *(const uint4*)(Arow + (c0 + 4) * 8);
  uint4 rb0 = *(const uint4*)(Brow + c0 * 8);
  uint4 rb1 = *(const uint4*)(Brow + (c0 + 4) * 8);
  *(uint4*)(&As[0][(c0 * 64 + r0) * 8]) = ra0;
  *(uint4*)(&As[0][((c0 + 4) * 64 + r0) * 8]) = ra1;
  *(uint4*)(&Bs[0][(c0 * 64 + r0) * 8]) = rb0;
  *(uint4*)(&Bs[0][((c0 + 4) * 64 + r0) * 8]) = rb1;
  __syncthreads();

  f32x4 acc[2][2] = {};
  const int NK = K >> 6;
  for (int ks = 0; ks < NK; ++ks) {
    const int cur = ks & 1;
    if (ks + 1 < NK) {
      const int ko = (ks + 1) << 6;
      ra0 = *(const uint4*)(Arow + ko + c0 * 8);
      ra1 = *(const uint4*)(Arow + ko + (c0 + 4) * 8);
      rb0 = *(const uint4*)(Brow + ko + c0 * 8);
      rb1 = *(const uint4*)(Brow + ko + (c0 + 4) * 8);
    }
#pragma unroll
    for (int kk = 0; kk < 2; ++kk) {
      const int kc = kk * 4 + fk;
      bf16x8 a0 = *(const bf16x8*)(&As[cur][(kc * 64 + wr * 32 + fr) * 8]);
      bf16x8 a1 = *(const bf16x8*)(&As[cur][(kc * 64 + wr * 32 + 16 + fr) * 8]);
      bf16x8 b0 = *(const bf16x8*)(&Bs[cur][(kc * 64 + wc * 32 + fr) * 8]);
      bf16x8 b1 = *(const bf16x8*)(&Bs[cur][(kc * 64 + wc * 32 + 16 + fr) * 8]);
      acc[0][0] = __builtin_amdgcn_mfma_f32_16x16x32_bf16(a0, b0, acc[0][0], 0, 0, 0);
      acc[0][1] = __builtin_amdgcn_mfma_f32_16x16x32_bf16(a0, b1, acc[0][1], 0, 0, 0);
      acc[1][0] = __builtin_amdgcn_mfma_f32_16x16x32_bf16(a1, b0, acc[1][0], 0, 0, 0);
      acc[1][1] = __builtin_amdgcn_mfma_f32_16x16x32_bf16(a1, b1, acc[1][1], 0, 0, 0);
    }
    if (ks + 1 < NK) {
      const int nxt = cur ^ 1;
      *(uint4*)(&As[nxt][(c0 * 64 + r0) * 8]) = ra0;
      *(uint4*)(&As[nxt][((c0 + 4) * 64 + r0) * 8]) = ra1;
      *(uint4*)(&Bs[nxt][(c0 * 64 + r0) * 8]) = rb0;
      *(uint4*)(&Bs[nxt][((c0 + 4) * 64 + r0) * 8]) = rb1;
    }
    __syncthreads();
  }

  if (ptype == 3) {
#pragma unroll
    for (int m = 0; m < 2; ++m)
#pragma unroll
      for (int n = 0; n < 2; ++n)
#pragma unroll
        for (int j = 0; j < 4; ++j) {
          int r = m0 + wr * 32 + m * 16 + fk * 4 + j;
          int c = nrow + wc * 32 + n * 16 + fr;
          float v = acc[m][n][j] + bias[c];
          if (relu) v = fmaxf(v, 0.f);
          if (residual) v += residual[(long)r * ldc + c];
          if (Cf) Cf[(long)r * ldc + c] = v;
          if (Cb) Cb[(long)r * ldc + c] = __float2bfloat16(v);
        }
    return;
  }

  // ---- pack epilogue: stage tile (f32, XOR-swizzled) in LDS over As ----
  float* Lt = (float*)As;
#pragma unroll
  for (int m = 0; m < 2; ++m)
#pragma unroll
    for (int n = 0; n < 2; ++n)
#pragma unroll
      for (int j = 0; j < 4; ++j) {
        int rl = wr * 32 + m * 16 + fk * 4 + j;
        int cl = wc * 32 + n * 16 + fr;
        Lt[rl * 64 + (cl ^ (rl & 31))] = acc[m][n][j] + bias[nrow + cl];
      }
  __syncthreads();

  if (ptype == 2) {
    const int d = t >> 2, sc = (t & 3) * 16;
    u16x8 o0, o1;
#pragma unroll
    for (int s = 0; s < 8; s++) {
      o0[s] = f2b(Lt[(sc + s) * 64 + (d ^ ((sc + s) & 31))]);
      o1[s] = f2b(Lt[(sc + 8 + s) * 64 + (d ^ ((sc + 8 + s) & 31))]);
    }
    __hip_bfloat16* dst = Vtp + ((long)(head * 64 + d)) * SEQ + m0 + sc;
    *(u16x8*)dst = o0;
    *(u16x8*)(dst + 8) = o1;
  } else {
    const float QS = (ptype == 0) ? 0.18033688011112042f : 1.0f;
    const int r = t >> 2, i0 = (t & 3) * 8;
    const float2* rp = rt + (long)(m0 + r) * 32 + i0;
    u16x8 lo, hi;
#pragma unroll
    for (int p = 0; p < 8; p++) {
      float a = Lt[r * 64 + ((i0 + p) ^ (r & 31))];
      float b = Lt[r * 64 + ((i0 + p + 32) ^ (r & 31))];
      float2 cs = rp[p];
      lo[p] = f2b((a * cs.x - b * cs.y) * QS);
      hi[p] = f2b((a * cs.y + b * cs.x) * QS);
    }
    __hip_bfloat16* dst =
        (ptype == 0 ? Qp : Kp) + ((long)head * SEQ + m0 + r) * 64 + i0;
    *(u16x8*)dst = lo;
    *(u16x8*)(dst + 32) = hi;
  }
}

// ---------------- split-KV flash attention ----------------------------------
__global__ __launch_bounds__(256) void attn_part_kernel(
    const __hip_bfloat16* __restrict__ Qp, const __hip_bfloat16* __restrict__ Kp,
    const __hip_bfloat16* __restrict__ Vtp, const float* __restrict__ mbias,
    const int* __restrict__ mtflag,
    __hip_bfloat16* __restrict__ Op, float* __restrict__ Ml,
    int causal, int csz) {
  const int qt = blockIdx.x, ch = blockIdx.y, head = blockIdx.z;
  const int kv0 = ch * csz;
  if (causal && kv0 > qt * 64 + 63) return;
  const int kvlen = causal ? min(csz, qt * 64 + 64 - kv0) : csz;
  const int nt = (kvlen + 63) >> 6;

  __shared__ __attribute__((aligned(16))) __hip_bfloat16 Ks[2][4096];
  __shared__ __attribute__((aligned(16))) __hip_bfloat16 Vs[4096];
  __shared__ __attribute__((aligned(16))) __hip_bfloat16 Ps[4096];
  const int t = threadIdx.x, w = t >> 6, lane = t & 63;
  const int fr = lane & 15, fk = lane >> 4;
  const int qr = qt * 64 + w * 16 + fr;
  const int wq0 = qt * 64 + w * 16;

  bf16x8 qa0, qa1;
  {
    const __hip_bfloat16* qp = Qp + ((long)head * SEQ + qr) * 64 + fk * 8;
    qa0 = *(const bf16x8*)qp;
    qa1 = *(const bf16x8*)(qp + 32);
  }
  const __hip_bfloat16* Kh = Kp + (long)head * SEQ * 64;
  const __hip_bfloat16* Vh = Vtp + (long)head * 64 * SEQ;
  const int skr = t & 63, skc = t >> 6;

  float m_i = -3e38f, l_i = 0.f;
  f32x4 o_[4] = {};
  const int sw2 = (fr & 7) << 4;

  uint4 vr0, vr1;
  {
    const __hip_bfloat16* ksrc = Kh + (long)(kv0 + skr) * 64 + skc * 8;
    gll16(ksrc, Ks[0] + t * 8);
    gll16(ksrc + 32, Ks[0] + t * 8 + 2048);
    const __hip_bfloat16* vsrc = Vh + (long)skr * SEQ + kv0 + skc * 8;
    vr0 = *(const uint4*)vsrc;
    vr1 = *(const uint4*)(vsrc + 32);
  }

  for (int tile = 0; tile < nt; ++tile) {
    const int cur = tile & 1;
    __syncthreads();
    *(uint4*)(Vs + t * 8) = vr0;
    *(uint4*)(Vs + t * 8 + 2048) = vr1;
    __syncthreads();
    if (tile + 1 < nt) {
      const int kb1 = kv0 + (tile + 1) * 64;
      const int nxt = cur ^ 1;
      const __hip_bfloat16* ksrc = Kh + (long)(kb1 + skr) * 64 + skc * 8;
      gll16(ksrc, Ks[nxt] + t * 8);
      gll16(ksrc + 32, Ks[nxt] + t * 8 + 2048);
      const __hip_bfloat16* vsrc = Vh + (long)skr * SEQ + kb1 + skc * 8;
      vr0 = *(const uint4*)vsrc;
      vr1 = *(const uint4*)(vsrc + 32);
    }
    const int kb = kv0 + tile * 64;
    const bool need = !causal || (kb <= wq0 + 15);
    if (need) {
      const bool diag = causal && (kb + 63 > wq0);
      const bool hasmask = mtflag[kb >> 6] != 0;

      f32x4 sacc[4];
      __builtin_amdgcn_s_setprio(1);
#pragma unroll
      for (int n = 0; n < 4; n++) {
        bf16x8 ka0 = *(const bf16x8*)(Ks[cur] + fk * 512 + (n * 16 + fr) * 8);
        bf16x8 ka1 = *(const bf16x8*)(Ks[cur] + (4 + fk) * 512 + (n * 16 + fr) * 8);
        f32x4 zz = {};
        zz = __builtin_amdgcn_mfma_f32_16x16x32_bf16(ka0, qa0, zz, 0, 0, 0);
        sacc[n] = __builtin_amdgcn_mfma_f32_16x16x32_bf16(ka1, qa1, zz, 0, 0, 0);
      }
      __builtin_amdgcn_s_setprio(0);

      float sv[4][4];
      float rm = -3e38f;
#pragma unroll
      for (int n = 0; n < 4; n++) {
        const int ka = kb + n * 16 + fk * 4;
        if (hasmask) {
          float4 mb = *(const float4*)(mbias + ka);
          sv[n][0] = sacc[n][0] + mb.x;
          sv[n][1] = sacc[n][1] + mb.y;
          sv[n][2] = sacc[n][2] + mb.z;
          sv[n][3] = sacc[n][3] + mb.w;
        } else {
          sv[n][0] = sacc[n][0]; sv[n][1] = sacc[n][1];
          sv[n][2] = sacc[n][2]; sv[n][3] = sacc[n][3];
        }
        if (diag) {
#pragma unroll
          for (int j = 0; j < 4; j++)
            if (ka + j > qr) sv[n][j] = -3e38f;
        }
#pragma unroll
        for (int j = 0; j < 4; j++) rm = fmaxf(rm, sv[n][j]);
      }
      rm = fmaxf(rm, __shfl_xor(rm, 16));
      rm = fmaxf(rm, __shfl_xor(rm, 32));
      if (!__all(rm <= m_i)) {
        float nm = fmaxf(m_i, rm);
        float f = exp2f(m_i - nm);
        l_i *= f;
#pragma unroll
        for (int n = 0; n < 4; n++) o_[n] *= f;
        m_i = nm;
      }
#pragma unroll
      for (int n = 0; n < 4; n++) {
        float p0 = exp2f(sv[n][0] - m_i);
        float p1 = exp2f(sv[n][1] - m_i);
        float p2 = exp2f(sv[n][2] - m_i);
        float p3 = exp2f(sv[n][3] - m_i);
        l_i += (p0 + p1) + (p2 + p3);
        ushort4 pk4;
        pk4.x = f2b(p0); pk4.y = f2b(p1); pk4.z = f2b(p2); pk4.w = f2b(p3);
        *(ushort4*)((char*)Ps + ((w * 2048 + fr * 128 + (n * 16 + fk * 4) * 2) ^ sw2)) = pk4;
      }

      __builtin_amdgcn_s_setprio(1);
#pragma unroll
      for (int s = 0; s < 2; s++) {
        bf16x8 pb = *(const bf16x8*)((char*)Ps + ((w * 2048 + fr * 128 + s * 64 + fk * 16) ^ sw2));
#pragma unroll
        for (int n = 0; n < 4; n++) {
          bf16x8 va = *(const bf16x8*)(Vs + (s * 4 + fk) * 512 + (n * 16 + fr) * 8);
          o_[n] = __builtin_amdgcn_mfma_f32_16x16x32_bf16(va, pb, o_[n], 0, 0, 0);
        }
      }
      __builtin_amdgcn_s_setprio(0);
    }
  }

  l_i += __shfl_xor(l_i, 16);
  l_i += __shfl_xor(l_i, 32);

  const long bid = ((long)head * 32 + qt) * gridDim.y + ch;
  __hip_bfloat16* Ob = Op + bid * 4096;
#pragma unroll
  for (int n = 0; n < 4; n++) {
    ushort4 ov;
    ov.x = f2b(o_[n][0]); ov.y = f2b(o_[n][1]);
    ov.z = f2b(o_[n][2]); ov.w = f2b(o_[n][3]);
    *(ushort4*)(Ob + (w * 16 + fr) * 64 + n * 16 + fk * 4) = ov;
  }
  if (fk == 0) {
    float2 ml = make_float2(m_i, l_i);
    *(float2*)(Ml + bid * 128 + (w * 16 + fr) * 2) = ml;
  }
}

// ---------------- combine partials -> bf16 O --------------------------------
__global__ __launch_bounds__(256) void attn_combine_kernel(
    const __hip_bfloat16* __restrict__ Op, const float* __restrict__ Ml,
    __hip_bfloat16* __restrict__ O, int ldo, int causal, int csz, int nch) {
  const int qt = blockIdx.x, head = blockIdx.y;
  const int nc = causal ? min(nch, (qt * 64 + 63) / csz + 1) : nch;
  const int t = threadIdx.x;
  const int row = t >> 2, c16 = (t & 3) * 16;
  const long bid0 = ((long)head * 32 + qt) * nch;
  float M = -3e38f;
  for (int c = 0; c < nc; c++) M = fmaxf(M, Ml[(bid0 + c) * 128 + row * 2]);
  float L = 0.f;
  float acc[16] = {};
  for (int c = 0; c < nc; c++) {
    float2 ml = *(const float2*)(Ml + (bid0 + c) * 128 + row * 2);
    float wg = exp2f(ml.x - M);
    L += wg * ml.y;
    const __hip_bfloat16* base = Op + (bid0 + c) * 4096 + row * 64 + c16;
    bf16x8 a = *(const bf16x8*)base;
    bf16x8 b = *(const bf16x8*)(base + 8);
#pragma unroll
    for (int e = 0; e < 8; e++) {
      acc[e] += wg * (float)a[e];
      acc[8 + e] += wg * (float)b[e];
    }
  }
  float invL = 1.f / fmaxf(L, 1e-20f);
  u16x8 o0, o1;
#pragma unroll
  for (int e = 0; e < 8; e++) {
    o0[e] = f2b(acc[e] * invL);
    o1[e] = f2b(acc[8 + e] * invL);
  }
  __hip_bfloat16* orow = O + (long)(qt * 64 + row) * ldo + head * 64 + c16;
  *(u16x8*)orow = o0;
  *(u16x8*)(orow + 8) = o1;
}

extern "C" void kernel_launch(void* const* d_in, const int* in_sizes, int n_in,
                              void* d_out, int out_size, void* d_ws, size_t ws_size,
                              hipStream_t stream) {
  const float* trg      = (const float*)d_in[0];
  const float* src_rep  = (const float*)d_in[1];
  const float* src_mask = (const float*)d_in[2];
  const float* emb_w    = (const float*)d_in[3];
  const float* emb_b    = (const float*)d_in[4];
  const float* sa_wqkv  = (const float*)d_in[5];
  const float* sa_bqkv  = (const float*)d_in[6];
  const float* sa_wo    = (const float*)d_in[7];
  const float* sa_bo    = (const float*)d_in[8];
  const float* ca_wqkv  = (const float*)d_in[9];
  const float* ca_bqkv  = (const float*)d_in[10];
  const float* ca_wo    = (const float*)d_in[11];
  const float* ca_bo    = (const float*)d_in[12];
  const float* ffn_w1   = (const float*)d_in[13];
  const float* ffn_b1   = (const float*)d_in[14];
  const float* ffn_w2   = (const float*)d_in[15];
  const float* ffn_b2   = (const float*)d_in[16];
  const float* ln_g     = (const float*)d_in[17];
  const float* ln_b     = (const float*)d_in[18];
  const float* lnf_g    = (const float*)d_in[19];
  const float* lnf_b    = (const float*)d_in[20];
  const float* gen_w    = (const float*)d_in[21];
  const float* gen_b    = (const float*)d_in[22];

  const float* srb = src_rep + (long)PMTN * DM;

  char* wsb = (char*)d_ws;
  float*          X    = (float*)wsb;                              // [0,4M)
  __hip_bfloat16* Hb   = (__hip_bfloat16*)(wsb + (4ul << 20));     // [4,6)
  __hip_bfloat16* MID  = (__hip_bfloat16*)(wsb + (6ul << 20));     // [6,14)
  __hip_bfloat16* Op   = MID;
  __hip_bfloat16* AO   = (__hip_bfloat16*)(wsb + (14ul << 20));    // [14,16)
  __hip_bfloat16* SRBb = (__hip_bfloat16*)(wsb + (16ul << 20));    // [16,18)
  float2*         rt   = (float2*)(wsb + (18ul << 20));            // 512K
  float*          mbias= (float*)(wsb + (18ul << 20) + 524288);    // 8K
  int*            mtfl = (int*)(wsb + (18ul << 20) + 532480);      // 128B
  float*          Ml   = (float*)(wsb + (19ul << 20));             // 512K
  __hip_bfloat16* Qp   = (__hip_bfloat16*)(wsb + (20ul << 20));    // 2M
  __hip_bfloat16* Kp   = (__hip_bfloat16*)(wsb + (22ul << 20));    // 2M
  __hip_bfloat16* Vtp  = (__hip_bfloat16*)(wsb + (24ul << 20));    // 2M
  __hip_bfloat16* Wt   = (__hip_bfloat16*)(wsb + (26ul << 20));    // 8M

  const int nch = 4;
  const int csz = SEQ / nch;

  prologue_kernel<<<8456, 256, 0, stream>>>(trg, emb_w, emb_b, X, srb, SRBb,
                                            rt, src_mask, mbias, mtfl);

  __hip_bfloat16* wqkvT  = Wt + 0;
  __hip_bfloat16* woT    = Wt + 786432;
  __hip_bfloat16* cwqkvT = Wt + 1048576;
  __hip_bfloat16* cwoT   = Wt + 1835008;
  __hip_bfloat16* w1T    = Wt + 2097152;
  __hip_bfloat16* w2T    = Wt + 3145728;

  for (int li = 0; li < 4; li++) {
    const float* bqkv  = sa_bqkv + (long)li * 3 * DM;
    const float* bo    = sa_bo + (long)li * DM;
    const float* cbqkv = ca_bqkv + (long)li * 3 * DM;
    const float* cbo   = ca_bo + (long)li * DM;
    const float* b1    = ffn_b1 + (long)li * DFFN;
    const float* b2    = ffn_b2 + (long)li * DM;
    const float* g0  = ln_g + (long)(li * 3 + 0) * DM;
    const float* bb0 = ln_b + (long)(li * 3 + 0) * DM;
    const float* g1  = ln_g + (long)(li * 3 + 1) * DM;
    const float* bb1 = ln_b + (long)(li * 3 + 1) * DM;
    const float* g2  = ln_g + (long)(li * 3 + 2) * DM;
    const float* bb2 = ln_b + (long)(li * 3 + 2) * DM;

    // ---- self attention (LN + this layer's weight transposes fused) ----
    ln_tr_kernel<<<1536, 256, 0, stream>>>(
        X, g0, bb0, Hb,
        sa_wqkv + (long)li * DM * 3 * DM, sa_wo + (long)li * DM * DM,
        ca_wqkv + (long)li * DM * 3 * DM, ca_wo + (long)li * DM * DM,
        ffn_w1 + (long)li * DM * DFFN, ffn_w2 + (long)li * DFFN * DM, Wt);
    gemm_bf16_64<<<dim3(24, 32), 256, 0, stream>>>(
        Hb, DM, nullptr, wqkvT, DM, bqkv, nullptr, nullptr, nullptr, DM,
        DM, 0, 1, rt, Qp, Kp, Vtp);
    attn_part_kernel<<<dim3(32, nch, 8), 256, 0, stream>>>(
        Qp, Kp, Vtp, mbias, mtfl, Op, Ml, 1, csz);
    attn_combine_kernel<<<dim3(32, 8), 256, 0, stream>>>(
        Op, Ml, AO, DM, 1, csz, nch);
    gemm_bf16_64<<<dim3(8, 32), 256, 0, stream>>>(
        AO, DM, nullptr, woT, DM, bo, X, X, nullptr, DM,
        DM, 0, 0, nullptr, nullptr, nullptr, nullptr);

    // ---- cross attention (Q + KV in one dispatch) ----
    ln_bf16_kernel<<<512, 256, 0, stream>>>(X, g1, bb1, Hb);
    gemm_bf16_64<<<dim3(24, 32), 256, 0, stream>>>(
        Hb, DM, SRBb, cwqkvT, DM, cbqkv, nullptr, nullptr, nullptr, DM,
        DM, 0, 2, rt, Qp, Kp, Vtp);
    attn_part_kernel<<<dim3(32, nch, 8), 256, 0, stream>>>(
        Qp, Kp, Vtp, mbias, mtfl, Op, Ml, 0, csz);
    attn_combine_kernel<<<dim3(32, 8), 256, 0, stream>>>(
        Op, Ml, AO, DM, 0, csz, nch);
    gemm_bf16_64<<<dim3(8, 32), 256, 0, stream>>>(
        AO, DM, nullptr, cwoT, DM, cbo, X, X, nullptr, DM,
        DM, 0, 0, nullptr, nullptr, nullptr, nullptr);

    // ---- FFN ----
    ln_bf16_kernel<<<512, 256, 0, stream>>>(X, g2, bb2, Hb);
    gemm_bf16_64<<<dim3(32, 32), 256, 0, stream>>>(
        Hb, DM, nullptr, w1T, DM, b1, nullptr, nullptr, MID, DFFN,
        DM, 1, 0, nullptr, nullptr, nullptr, nullptr);
    gemm_bf16_64<<<dim3(8, 32), 256, 0, stream>>>(
        MID, DFFN, nullptr, w2T, DFFN, b2, X, X, nullptr, DM,
        DFFN, 0, 0, nullptr, nullptr, nullptr, nullptr);
  }

  ln_gen_kernel<<<512, 256, 0, stream>>>(X, lnf_g, lnf_b, gen_w, gen_b,
                                         (float*)d_out);
}